// Round 2
// baseline (674.622 us; speedup 1.0000x reference)
//
#include <hip/hip_runtime.h>

#define PATCH 4
#define EMBED 96
#define HIN 512
#define WIN 512
#define HP 128
#define WP 128
#define BATCH 8
#define CHAN 8   // 3 rgb + 4 hs + 1 dem

// v3: v2's write-locality structure, but register-pressure-safe (v2 spilled:
// 64 VGPR alloc vs ~95 live -> scratch thrash, FETCH 346MB / WRITE 873MB).
// Thread owns 2 wp-adjacent patches = 32 VGPRs of pixel data:
//   patch0 = floats 0..3 of each of 4 rows (qa[r])
//   patch1 = floats 4..7 of each of 4 rows (qb[r])
// Per e: 32 FMA (weights uniform -> SGPR), one float2 store:
//   wave = one hp row -> 64 lanes x 8B = 512B contiguous store,
//   block = 4 hp rows -> 2KB contiguous per e-slice.
// Grid 2048 = 64 planes x 32 hp-quads; XCD swizzle pins 8 planes per XCD.
// VGPR budget ~50 -> 8 waves/EU, whole grid co-resident.
__global__ __launch_bounds__(256, 8)
void patch_embed_kernel(const float* __restrict__ rgb,
                        const float* __restrict__ hs,
                        const float* __restrict__ dem,
                        const float* __restrict__ W,
                        const float* __restrict__ bias,
                        float* __restrict__ out) {
    const int d     = blockIdx.x;            // 0..2047
    const int xcd   = d & 7;
    const int j     = d >> 3;                // 0..255
    const int plane = (j >> 5) * 8 + xcd;    // 0..63 == b*8 + c (bijective)
    const int hp4   = j & 31;                // group of 4 hp rows
    const int b = plane >> 3;
    const int c = plane & 7;

    const int tid  = threadIdx.x;
    const int hp   = hp4 * 4 + (tid >> 6);   // wave w -> hp row
    const int lane = tid & 63;
    const int wp   = lane * 2;               // 2 adjacent patches per thread

    // channel -> source plane (concat order: rgb[0..2], hs[3..6], dem[7])
    const float* src;
    if (c < 3)      src = rgb + (size_t)(b * 3 + c)       * (HIN * WIN);
    else if (c < 7) src = hs  + (size_t)(b * 4 + (c - 3)) * (HIN * WIN);
    else            src = dem + (size_t)b                 * (HIN * WIN);

    const float* base = src + (size_t)(hp * PATCH) * WIN + wp * PATCH;

    // 2 patches: 4 rows x 8 contiguous floats -> qa[r] (patch0), qb[r] (patch1)
    float4 qa[4], qb[4];
    #pragma unroll
    for (int r = 0; r < 4; ++r) {
        qa[r] = *(const float4*)(base + (size_t)r * WIN);
        qb[r] = *(const float4*)(base + (size_t)r * WIN + 4);
    }

    // out[b, c*96+e, hp, wp..wp+1]; e-slice stride = HP*WP floats (64 KB)
    float* outp = out + (((size_t)plane * EMBED * HP + hp) * WP + wp);

    #pragma unroll 4
    for (int e = 0; e < EMBED; ++e) {
        const float bb = bias[e];
        float a0 = bb, a1 = bb;
        #pragma unroll
        for (int r = 0; r < 4; ++r) {
            const float4 w = *(const float4*)(W + e * 16 + r * 4);  // uniform -> s_load
            a0 = fmaf(qa[r].x, w.x, a0);
            a0 = fmaf(qa[r].y, w.y, a0);
            a0 = fmaf(qa[r].z, w.z, a0);
            a0 = fmaf(qa[r].w, w.w, a0);
            a1 = fmaf(qb[r].x, w.x, a1);
            a1 = fmaf(qb[r].y, w.y, a1);
            a1 = fmaf(qb[r].z, w.z, a1);
            a1 = fmaf(qb[r].w, w.w, a1);
        }
        *(float2*)(outp + (size_t)e * (HP * WP)) = make_float2(a0, a1);
    }
}

extern "C" void kernel_launch(void* const* d_in, const int* in_sizes, int n_in,
                              void* d_out, int out_size, void* d_ws, size_t ws_size,
                              hipStream_t stream) {
    const float* rgb  = (const float*)d_in[0];
    const float* hs   = (const float*)d_in[1];
    const float* dem  = (const float*)d_in[2];
    const float* W    = (const float*)d_in[3];
    const float* bias = (const float*)d_in[4];
    float* out = (float*)d_out;

    const int grid = BATCH * CHAN * (HP / 4);   // 8*8*32 = 2048 blocks
    patch_embed_kernel<<<grid, 256, 0, stream>>>(rgb, hs, dem, W, bias, out);
}

// Round 3
// 469.852 us; speedup vs baseline: 1.4358x; 1.4358x over previous
//
#include <hip/hip_runtime.h>

#define PATCH 4
#define EMBED 96
#define HIN 512
#define WIN 512
#define HP 128
#define WP 128
#define BATCH 8
#define CHAN 8   // 3 rgb + 4 hs + 1 dem

// v4: register-allocation-robust rewrite of the write-locality structure.
// Lesson from v2/v3 counters: hipcc allocates VGPRs at ~half the launch_bounds
// cap (one occupancy step above the declared minimum) and will spill pixel
// data held across the 96-iter e-loop. v3 (cap 64 -> alloc 32, ~50 live)
// spilled -> FETCH 640MB. Fix: 512-thread block with __launch_bounds__(512,2)
// -> cap 256; even a halving allocator lands >=64 >= ~50 live. No arrays --
// named float4 scalars only.
//
// Geometry: block = (plane, hp8-group): 8 hp rows x 128 wp x all 96 e.
//   wave w (of 8) = hp row; lane*2 = wp pair; thread holds 2 patches
//   (qa0..3 = patch wp rows 0..3, qb0..3 = patch wp+1).
//   Per e: 32 FMA (weights uniform -> scalar cache), one float2 store:
//   wave = 512B contiguous, block e-slice = 8 rows x 512B = 4KB contiguous.
// Grid 1024 = 64 planes x 16 hp-groups, all co-resident (4 blk/CU);
// XCD swizzle pins 8 planes per XCD for read L2 locality.
__global__ __launch_bounds__(512, 2)
void patch_embed_kernel(const float* __restrict__ rgb,
                        const float* __restrict__ hs,
                        const float* __restrict__ dem,
                        const float* __restrict__ W,
                        const float* __restrict__ bias,
                        float* __restrict__ out) {
    const int d     = blockIdx.x;            // 0..1023
    const int xcd   = d & 7;
    const int j     = d >> 3;                // 0..127
    const int plane = (j >> 4) * 8 + xcd;    // 0..63 == b*8 + c (bijective)
    const int hp8   = j & 15;                // group of 8 hp rows
    const int b = plane >> 3;
    const int c = plane & 7;

    const int tid  = threadIdx.x;            // 0..511
    const int hp   = hp8 * 8 + (tid >> 6);   // wave -> hp row
    const int lane = tid & 63;
    const int wp   = lane * 2;               // 2 adjacent patches per thread

    // channel -> source plane (concat order: rgb[0..2], hs[3..6], dem[7])
    const float* src;
    if (c < 3)      src = rgb + (size_t)(b * 3 + c)       * (HIN * WIN);
    else if (c < 7) src = hs  + (size_t)(b * 4 + (c - 3)) * (HIN * WIN);
    else            src = dem + (size_t)b                 * (HIN * WIN);

    const float* base = src + (size_t)(hp * PATCH) * WIN + wp * PATCH;

    // 2 patches: 4 rows x 8 contiguous floats. Named scalars, no arrays.
    const float4 qa0 = *(const float4*)(base);
    const float4 qb0 = *(const float4*)(base + 4);
    const float4 qa1 = *(const float4*)(base + WIN);
    const float4 qb1 = *(const float4*)(base + WIN + 4);
    const float4 qa2 = *(const float4*)(base + 2 * WIN);
    const float4 qb2 = *(const float4*)(base + 2 * WIN + 4);
    const float4 qa3 = *(const float4*)(base + 3 * WIN);
    const float4 qb3 = *(const float4*)(base + 3 * WIN + 4);

    // out[b, c*96+e, hp, wp..wp+1]; e-slice stride = HP*WP floats (64 KB)
    float* outp = out + (((size_t)plane * EMBED * HP + hp) * WP + wp);

    #pragma unroll 4
    for (int e = 0; e < EMBED; ++e) {
        const float4 w0 = *(const float4*)(W + e * 16);
        const float4 w1 = *(const float4*)(W + e * 16 + 4);
        const float4 w2 = *(const float4*)(W + e * 16 + 8);
        const float4 w3 = *(const float4*)(W + e * 16 + 12);
        const float bb = bias[e];
        float a0 = bb, a1 = bb;

        a0 = fmaf(qa0.x, w0.x, a0); a0 = fmaf(qa0.y, w0.y, a0);
        a0 = fmaf(qa0.z, w0.z, a0); a0 = fmaf(qa0.w, w0.w, a0);
        a0 = fmaf(qa1.x, w1.x, a0); a0 = fmaf(qa1.y, w1.y, a0);
        a0 = fmaf(qa1.z, w1.z, a0); a0 = fmaf(qa1.w, w1.w, a0);
        a0 = fmaf(qa2.x, w2.x, a0); a0 = fmaf(qa2.y, w2.y, a0);
        a0 = fmaf(qa2.z, w2.z, a0); a0 = fmaf(qa2.w, w2.w, a0);
        a0 = fmaf(qa3.x, w3.x, a0); a0 = fmaf(qa3.y, w3.y, a0);
        a0 = fmaf(qa3.z, w3.z, a0); a0 = fmaf(qa3.w, w3.w, a0);

        a1 = fmaf(qb0.x, w0.x, a1); a1 = fmaf(qb0.y, w0.y, a1);
        a1 = fmaf(qb0.z, w0.z, a1); a1 = fmaf(qb0.w, w0.w, a1);
        a1 = fmaf(qb1.x, w1.x, a1); a1 = fmaf(qb1.y, w1.y, a1);
        a1 = fmaf(qb1.z, w1.z, a1); a1 = fmaf(qb1.w, w1.w, a1);
        a1 = fmaf(qb2.x, w2.x, a1); a1 = fmaf(qb2.y, w2.y, a1);
        a1 = fmaf(qb2.z, w2.z, a1); a1 = fmaf(qb2.w, w2.w, a1);
        a1 = fmaf(qb3.x, w3.x, a1); a1 = fmaf(qb3.y, w3.y, a1);
        a1 = fmaf(qb3.z, w3.z, a1); a1 = fmaf(qb3.w, w3.w, a1);

        *(float2*)(outp + (size_t)e * (HP * WP)) = make_float2(a0, a1);
    }
}

extern "C" void kernel_launch(void* const* d_in, const int* in_sizes, int n_in,
                              void* d_out, int out_size, void* d_ws, size_t ws_size,
                              hipStream_t stream) {
    const float* rgb  = (const float*)d_in[0];
    const float* hs   = (const float*)d_in[1];
    const float* dem  = (const float*)d_in[2];
    const float* W    = (const float*)d_in[3];
    const float* bias = (const float*)d_in[4];
    float* out = (float*)d_out;

    const int grid = BATCH * CHAN * (HP / 8);   // 8*8*16 = 1024 blocks
    patch_embed_kernel<<<grid, 512, 0, stream>>>(rgb, hs, dem, W, bias, out);
}